// Round 1
// baseline (734.358 us; speedup 1.0000x reference)
//
#include <hip/hip_runtime.h>

// EfficientDet head: 5 levels (P3..P7), cls/box subnets of 3 separable convs
// (depthwise 3x3 SAME + pointwise 64x64 + bias + per-level BN + swish), then
// score (810x64) / pred (36x64) separable-conv heads. All fp32.
//
// Plan: 4 launches.
//   stage_kernel x3 (depth 0,1,2): all levels, both subnets, fused dw+pw+bn+swish
//   head_kernel  x1: score head (split into 4 o-range blocks) + pred head
// ws: two ping-pong activation buffers, each [2 subnets][B,C,H,W packed by level].

namespace {
constexpr int CH = 64;
constexpr int NCD = 3;
constexpr long SSTRIDE = 2793472;  // floats per subnet activation buffer
constexpr int TPI = 86;            // tiles per image (64+16+4+1+1)
constexpr int TPS = 86 * 8;        // tiles per subnet = 688
constexpr float BNEPS = 1e-3f;
}

__device__ __forceinline__ int wave_id() {
  // threadIdx.x >> 6 is wave-uniform; make that explicit so weight reads
  // indexed by it become scalar (s_load) instead of per-lane vector loads.
  return __builtin_amdgcn_readfirstlane((int)(threadIdx.x >> 6));
}

__device__ __forceinline__ void decode_tile(int u, int& lvl, int& tx0, int& ty0) {
  int tile, tpr;
  if (u < 64)       { lvl = 0; tile = u;      tpr = 8; }
  else if (u < 80)  { lvl = 1; tile = u - 64; tpr = 4; }
  else if (u < 84)  { lvl = 2; tile = u - 80; tpr = 2; }
  else if (u == 84) { lvl = 3; tile = 0;      tpr = 1; }
  else              { lvl = 4; tile = 0;      tpr = 1; }
  tx0 = (tile % tpr) * 8;
  ty0 = (tile / tpr) * 8;
}

__device__ __forceinline__ long lvl_off(int lvl) {
  switch (lvl) {
    case 0: return 0L;
    case 1: return 2097152L;
    case 2: return 2621440L;
    case 3: return 2752512L;
    default: return 2785280L;
  }
}

__device__ __forceinline__ long head_out_base(int subnet, int lvl) {
  if (subnet == 0) {  // logits, OC=810
    switch (lvl) {
      case 0: return 0L;
      case 1: return 26542080L;
      case 2: return 33177600L;
      case 3: return 34836480L;
      default: return 35251200L;
    }
  } else {            // bbox, OC=36
    switch (lvl) {
      case 0: return 35354880L;
      case 1: return 36534528L;
      case 2: return 36829440L;
      case 3: return 36903168L;
      default: return 36921600L;
    }
  }
}

// One separable-conv block (dw3x3 + pw64x64 + bias + BN + swish) for one
// 8x8 pixel tile of one (subnet, level, image). Grid = 2*688.
__global__ __launch_bounds__(256) void stage_kernel(
    const float* __restrict__ q0, const float* __restrict__ q1,
    const float* __restrict__ q2, const float* __restrict__ q3,
    const float* __restrict__ q4,
    const float* __restrict__ buf_in, float* __restrict__ buf_out,
    const float* __restrict__ cls_dw, const float* __restrict__ cls_pw,
    const float* __restrict__ cls_pwb,
    const float* __restrict__ box_dw, const float* __restrict__ box_pw,
    const float* __restrict__ box_pwb,
    const float* __restrict__ bng0, const float* __restrict__ bnb0,
    const float* __restrict__ bnm0, const float* __restrict__ bnv0,
    const float* __restrict__ bng1, const float* __restrict__ bnb1,
    const float* __restrict__ bnm1, const float* __restrict__ bnv1,
    int depth)
{
  __shared__ float s_in[CH * 120];  // [c][10 rows][pitch 12] -> 2-way bank alias only
  __shared__ float s_dw[CH * 64];   // [c][px]

  int bx = blockIdx.x;
  int subnet = bx / TPS;
  int r = bx - subnet * TPS;
  int n = r / TPI;
  int u = r - n * TPI;
  int lvl, tx0, ty0;
  decode_tile(u, lvl, tx0, ty0);
  int H = 64 >> lvl;

  const float* in;
  if (depth == 0) {
    in = (lvl == 0) ? q0 : (lvl == 1) ? q1 : (lvl == 2) ? q2 : (lvl == 3) ? q3 : q4;
  } else {
    in = buf_in + (long)subnet * SSTRIDE + lvl_off(lvl);
  }
  const float* dww = subnet ? box_dw : cls_dw;   // (NC,C,9)
  const float* pww = subnet ? box_pw : cls_pw;   // (NC,C,C) [d][o][c]
  const float* pwb = subnet ? box_pwb : cls_pwb; // (NC,C)
  const float* bg = subnet ? bng1 : bng0;        // (NL,NC,C)
  const float* bb = subnet ? bnb1 : bnb0;
  const float* bm = subnet ? bnm1 : bnm0;
  const float* bv = subnet ? bnv1 : bnv0;

  int t = threadIdx.x;
  long img_base = (long)n * CH * H * H;

  // Phase A: load 10x10 halo tile for all 64 channels (zeros outside).
  for (int idx = t; idx < CH * 100; idx += 256) {
    int c = idx / 100;
    int rem = idx - c * 100;
    int yy = rem / 10;
    int xx = rem - yy * 10;
    int gy = ty0 - 1 + yy, gx = tx0 - 1 + xx;
    float v = 0.f;
    if (gy >= 0 && gy < H && gx >= 0 && gx < H)
      v = in[img_base + ((long)c * H + gy) * H + gx];
    s_in[c * 120 + yy * 12 + xx] = v;
  }
  __syncthreads();

  int px = t & 63;
  int pxx = px & 7, pxy = px >> 3;
  int w = wave_id();

  // Phase B: depthwise 3x3 (c is wave-uniform -> scalar weight loads).
  #pragma unroll
  for (int k = 0; k < 16; ++k) {
    int c = w + 4 * k;
    const float* dwc = dww + ((long)depth * CH + c) * 9;
    const float* base = &s_in[c * 120 + pxy * 12 + pxx];
    float a = 0.f;
    #pragma unroll
    for (int dy = 0; dy < 3; ++dy)
      #pragma unroll
      for (int dx = 0; dx < 3; ++dx)
        a = fmaf(dwc[dy * 3 + dx], base[dy * 12 + dx], a);
    s_dw[c * 64 + px] = a;
  }
  __syncthreads();

  // Phase C: pointwise 64->64, o = w + 4k (wave-uniform -> scalar weights).
  float acc[16];
  #pragma unroll
  for (int k = 0; k < 16; ++k) acc[k] = 0.f;
  const float* pwd = pww + (long)depth * CH * CH;
  for (int c = 0; c < CH; ++c) {
    float v = s_dw[c * 64 + px];
    #pragma unroll
    for (int k = 0; k < 16; ++k)
      acc[k] = fmaf(pwd[(w + 4 * k) * CH + c], v, acc[k]);
  }

  int ox = tx0 + pxx, oy = ty0 + pxy;
  if (ox < H && oy < H) {
    float* outp = buf_out + (long)subnet * SSTRIDE + lvl_off(lvl) + img_base;
    int bno = (lvl * NCD + depth) * CH;
    #pragma unroll
    for (int k = 0; k < 16; ++k) {
      int o = w + 4 * k;
      float scale = bg[bno + o] * rsqrtf(bv[bno + o] + BNEPS);
      float z = fmaf(acc[k] + pwb[depth * CH + o] - bm[bno + o], scale, bb[bno + o]);
      float y = z / (1.f + __expf(-z));
      outp[((long)o * H + oy) * H + ox] = y;
    }
  }
}

// Heads: dw3x3 + pw + bias (no BN/swish). Grid = 5*688:
// sb 0..3 = score head o-range quarters (from cls buffer), sb 4 = pred head.
__global__ __launch_bounds__(256) void head_kernel(
    const float* __restrict__ buf_in, float* __restrict__ out,
    const float* __restrict__ score_dw, const float* __restrict__ score_pw,
    const float* __restrict__ score_b,
    const float* __restrict__ pred_dw, const float* __restrict__ pred_pw,
    const float* __restrict__ pred_b)
{
  __shared__ float s_in[CH * 120];
  __shared__ float s_dw[CH * 64];

  int bx = blockIdx.x;
  int sb = bx / TPS;
  int r = bx - sb * TPS;
  int n = r / TPI;
  int u = r - n * TPI;
  int lvl, tx0, ty0;
  decode_tile(u, lvl, tx0, ty0);
  int H = 64 >> lvl;

  int subnet = (sb == 4) ? 1 : 0;
  int OC = subnet ? 36 : 810;
  int o_lo = subnet ? 0 : sb * 204;
  int o_hi = subnet ? 36 : ((sb == 3) ? 810 : o_lo + 204);

  const float* in = buf_in + (long)subnet * SSTRIDE + lvl_off(lvl);
  const float* dww = subnet ? pred_dw : score_dw;  // (C,1,3,3)
  const float* pw = subnet ? pred_pw : score_pw;   // (OC,64)
  const float* bias = subnet ? pred_b : score_b;   // (OC)

  int t = threadIdx.x;
  long img_base = (long)n * CH * H * H;

  for (int idx = t; idx < CH * 100; idx += 256) {
    int c = idx / 100;
    int rem = idx - c * 100;
    int yy = rem / 10;
    int xx = rem - yy * 10;
    int gy = ty0 - 1 + yy, gx = tx0 - 1 + xx;
    float v = 0.f;
    if (gy >= 0 && gy < H && gx >= 0 && gx < H)
      v = in[img_base + ((long)c * H + gy) * H + gx];
    s_in[c * 120 + yy * 12 + xx] = v;
  }
  __syncthreads();

  int px = t & 63;
  int pxx = px & 7, pxy = px >> 3;
  int w = wave_id();

  #pragma unroll
  for (int k = 0; k < 16; ++k) {
    int c = w + 4 * k;
    const float* dwc = dww + c * 9;
    const float* base = &s_in[c * 120 + pxy * 12 + pxx];
    float a = 0.f;
    #pragma unroll
    for (int dy = 0; dy < 3; ++dy)
      #pragma unroll
      for (int dx = 0; dx < 3; ++dx)
        a = fmaf(dwc[dy * 3 + dx], base[dy * 12 + dx], a);
    s_dw[c * 64 + px] = a;
  }
  __syncthreads();

  // Cache this pixel's 64 depthwise outputs in registers (static indices only).
  float dv[64];
  #pragma unroll
  for (int c = 0; c < 64; ++c) dv[c] = s_dw[c * 64 + px];

  int ox = tx0 + pxx, oy = ty0 + pxy;
  bool valid = (ox < H) && (oy < H);
  float* outp = out + head_out_base(subnet, lvl);

  // o = o_lo + w + 4k; chunks of 8 accumulators. Weight indices clamped
  // (uniform, always in-bounds) so the FMA block stays branch-free.
  for (int ob = o_lo + w; ob < o_hi; ob += 32) {
    int oidx[8];
    #pragma unroll
    for (int k = 0; k < 8; ++k) {
      int o = ob + 4 * k;
      oidx[k] = (o < o_hi) ? o : (o_hi - 1);
    }
    float acc[8];
    #pragma unroll
    for (int k = 0; k < 8; ++k) acc[k] = 0.f;
    #pragma unroll
    for (int c = 0; c < 64; ++c) {
      #pragma unroll
      for (int k = 0; k < 8; ++k)
        acc[k] = fmaf(pw[(long)oidx[k] * 64 + c], dv[c], acc[k]);
    }
    if (valid) {
      #pragma unroll
      for (int k = 0; k < 8; ++k) {
        int o = ob + 4 * k;
        if (o < o_hi)
          outp[((long)(n * OC + o) * H + oy) * H + ox] = acc[k] + bias[o];
      }
    }
  }
}

extern "C" void kernel_launch(void* const* d_in, const int* in_sizes, int n_in,
                              void* d_out, int out_size, void* d_ws, size_t ws_size,
                              hipStream_t stream) {
  const float* p3 = (const float*)d_in[0];
  const float* p4 = (const float*)d_in[1];
  const float* p5 = (const float*)d_in[2];
  const float* p6 = (const float*)d_in[3];
  const float* p7 = (const float*)d_in[4];
  const float* cls_dw = (const float*)d_in[5];
  const float* cls_pw = (const float*)d_in[6];
  const float* cls_pwb = (const float*)d_in[7];
  const float* box_dw = (const float*)d_in[8];
  const float* box_pw = (const float*)d_in[9];
  const float* box_pwb = (const float*)d_in[10];
  const float* bn_cls_g = (const float*)d_in[11];
  const float* bn_cls_b = (const float*)d_in[12];
  const float* bn_cls_m = (const float*)d_in[13];
  const float* bn_cls_v = (const float*)d_in[14];
  const float* bn_box_g = (const float*)d_in[15];
  const float* bn_box_b = (const float*)d_in[16];
  const float* bn_box_m = (const float*)d_in[17];
  const float* bn_box_v = (const float*)d_in[18];
  const float* score_dw = (const float*)d_in[19];
  const float* score_pw = (const float*)d_in[20];
  const float* score_b = (const float*)d_in[21];
  const float* pred_dw = (const float*)d_in[22];
  const float* pred_pw = (const float*)d_in[23];
  const float* pred_b = (const float*)d_in[24];

  float* ws = (float*)d_ws;
  float* buf0 = ws;                   // 2 * SSTRIDE floats
  float* buf1 = ws + 2 * SSTRIDE;     // 2 * SSTRIDE floats (total ~44.7 MB)
  float* out = (float*)d_out;

  dim3 blk(256);
  stage_kernel<<<dim3(2 * TPS), blk, 0, stream>>>(
      p3, p4, p5, p6, p7, nullptr, buf0,
      cls_dw, cls_pw, cls_pwb, box_dw, box_pw, box_pwb,
      bn_cls_g, bn_cls_b, bn_cls_m, bn_cls_v,
      bn_box_g, bn_box_b, bn_box_m, bn_box_v, 0);
  stage_kernel<<<dim3(2 * TPS), blk, 0, stream>>>(
      p3, p4, p5, p6, p7, buf0, buf1,
      cls_dw, cls_pw, cls_pwb, box_dw, box_pw, box_pwb,
      bn_cls_g, bn_cls_b, bn_cls_m, bn_cls_v,
      bn_box_g, bn_box_b, bn_box_m, bn_box_v, 1);
  stage_kernel<<<dim3(2 * TPS), blk, 0, stream>>>(
      p3, p4, p5, p6, p7, buf1, buf0,
      cls_dw, cls_pw, cls_pwb, box_dw, box_pw, box_pwb,
      bn_cls_g, bn_cls_b, bn_cls_m, bn_cls_v,
      bn_box_g, bn_box_b, bn_box_m, bn_box_v, 2);
  head_kernel<<<dim3(5 * TPS), blk, 0, stream>>>(
      buf0, out, score_dw, score_pw, score_b, pred_dw, pred_pw, pred_b);
}

// Round 7
// 554.670 us; speedup vs baseline: 1.3240x; 1.3240x over previous
//
#include <hip/hip_runtime.h>

// EfficientDet head, fp32. 7 launches:
//   prep_stage:  transpose cls/box pointwise weights to [d][c][o]  (stored in d_out head)
//   stage x3:    dw3x3(in-place LDS) + pw(64x64, s_load_x16 weights) + BN + swish
//   head_dw:     heads' depthwise, written transposed dv[c][pixel]
//   prep_head:   transpose score/pred pointwise weights to [c][o] (padded to 896/64)
//   head_gemm:   register GEMM, dv[64] in VGPRs, 64px x 128o chunk per wave, no LDS
//
// ws layout (floats), exactly 4*S (proven size):
//   [0, 2S)   buf0 (stage ping A); head wT/wpT tables overwrite after head_dw consumes
//   [2S, 4S)  buf1 (stage ping B); reused as dv[subnet][c][pixel] (exactly fits)
// wcT (stage pw weights, 24576 floats) lives at d_out[0..24576) — consumed by the
// stages, then fully overwritten by head_gemm.

namespace {
constexpr int CH = 64;
constexpr int NCD = 3;
constexpr long S = 2793472;        // floats per subnet activation buffer
constexpr int TPI = 86;            // tiles per image (64+16+4+1+1)
constexpr int TPS = 688;           // tiles per subnet (86*8)
constexpr int TOT = 43648;         // total pixels per (subnet, channel)
constexpr float BNEPS = 1e-3f;
constexpr int PXT = 682;           // pixel tiles of 64 (43648/64)
constexpr int WSTR_S = 896;        // padded score weight row (7 chunks of 128)
constexpr int NSJ = PXT * 7;       // score wave-jobs (o-chunks of 128)
constexpr int NPJ = PXT;           // pred wave-jobs (one 48-wide chunk)
constexpr int GEMM_BLOCKS = (NSJ + NPJ) / 4;  // 5456/4 = 1364
}

__device__ __forceinline__ int wave_id() {
  return __builtin_amdgcn_readfirstlane((int)(threadIdx.x >> 6));
}

__device__ __forceinline__ void decode_tile(int u, int& lvl, int& tx0, int& ty0) {
  int tile, tpr;
  if (u < 64)       { lvl = 0; tile = u;      tpr = 8; }
  else if (u < 80)  { lvl = 1; tile = u - 64; tpr = 4; }
  else if (u < 84)  { lvl = 2; tile = u - 80; tpr = 2; }
  else if (u == 84) { lvl = 3; tile = 0;      tpr = 1; }
  else              { lvl = 4; tile = 0;      tpr = 1; }
  tx0 = (tile % tpr) * 8;
  ty0 = (tile / tpr) * 8;
}

__device__ __forceinline__ long lvl_off(int lvl) {  // into [c][H][W] level-packed subnet buf
  switch (lvl) {
    case 0: return 0L;
    case 1: return 2097152L;
    case 2: return 2621440L;
    case 3: return 2752512L;
    default: return 2785280L;
  }
}

__device__ __forceinline__ int lvl_lb(int lvl) {    // pixel-flat level base
  switch (lvl) {
    case 0: return 0;
    case 1: return 32768;
    case 2: return 40960;
    case 3: return 43008;
    default: return 43520;
  }
}

__device__ __forceinline__ long head_out_base(int subnet, int lvl) {
  if (subnet == 0) {
    switch (lvl) {
      case 0: return 0L;
      case 1: return 26542080L;
      case 2: return 33177600L;
      case 3: return 34836480L;
      default: return 35251200L;
    }
  } else {
    switch (lvl) {
      case 0: return 35354880L;
      case 1: return 36534528L;
      case 2: return 36829440L;
      case 3: return 36903168L;
      default: return 36921600L;
    }
  }
}

// ---- prep: stage pointwise weights (NC,o,c) -> wcT[(subnet*3+d)*64+c][o] ----
__global__ __launch_bounds__(256) void prep_stage_kernel(
    const float* __restrict__ cls_pw, const float* __restrict__ box_pw,
    float* __restrict__ wcT) {
  int i = blockIdx.x * 256 + threadIdx.x;
  if (i >= 2 * NCD * CH * CH) return;
  int o = i & 63;
  int c = (i >> 6) & 63;
  int sd = i >> 12;                       // subnet*3 + d
  const float* src = (sd < NCD) ? cls_pw : box_pw;
  int d = (sd < NCD) ? sd : sd - NCD;
  wcT[i] = src[(d * CH + o) * CH + c];
}

// ---- prep: head pw weights -> wT[c][896] (score, zero-padded), wpT[c][64] (pred) ----
__global__ __launch_bounds__(256) void prep_head_kernel(
    const float* __restrict__ score_pw, const float* __restrict__ pred_pw,
    float* __restrict__ wT, float* __restrict__ wpT) {
  int i = blockIdx.x * 256 + threadIdx.x;
  if (i < CH * WSTR_S) {
    int c = i / WSTR_S;
    int o = i - c * WSTR_S;
    wT[i] = (o < 810) ? score_pw[o * CH + c] : 0.f;
  } else {
    int j = i - CH * WSTR_S;
    if (j < CH * CH) {
      int c = j >> 6;
      int o = j & 63;
      wpT[j] = (o < 36) ? pred_pw[o * CH + c] : 0.f;
    }
  }
}

// ---- subnet stage: dw3x3 + pw64x64 + bias + BN + swish ----
__global__ __launch_bounds__(256) void stage_kernel(
    const float* __restrict__ q0, const float* __restrict__ q1,
    const float* __restrict__ q2, const float* __restrict__ q3,
    const float* __restrict__ q4,
    const float* __restrict__ buf_in, float* __restrict__ buf_out,
    const float* __restrict__ cls_dw, const float* __restrict__ box_dw,
    const float* __restrict__ wcT,
    const float* __restrict__ cls_pwb, const float* __restrict__ box_pwb,
    const float* __restrict__ bng0, const float* __restrict__ bnb0,
    const float* __restrict__ bnm0, const float* __restrict__ bnv0,
    const float* __restrict__ bng1, const float* __restrict__ bnb1,
    const float* __restrict__ bnm1, const float* __restrict__ bnv1,
    int depth)
{
  __shared__ float s_in[CH * 120];   // [c][10 rows][pitch 12]; dw result overwrites in place

  int bx = blockIdx.x;
  int subnet = bx / TPS;
  int r = bx - subnet * TPS;
  int n = r / TPI;
  int u = r - n * TPI;
  int lvl, tx0, ty0;
  decode_tile(u, lvl, tx0, ty0);
  int H = 64 >> lvl;

  const float* in;
  if (depth == 0) {
    in = (lvl == 0) ? q0 : (lvl == 1) ? q1 : (lvl == 2) ? q2 : (lvl == 3) ? q3 : q4;
  } else {
    in = buf_in + (long)subnet * S + lvl_off(lvl);
  }
  const float* dww = subnet ? box_dw : cls_dw;    // (NC,C,9)
  const float* pwb = subnet ? box_pwb : cls_pwb;  // (NC,C)
  const float* bg = subnet ? bng1 : bng0;         // (NL,NC,C)
  const float* bb = subnet ? bnb1 : bnb0;
  const float* bm = subnet ? bnm1 : bnm0;
  const float* bv = subnet ? bnv1 : bnv0;

  int t = threadIdx.x;
  long img_base = (long)n * CH * H * H;

  // Phase A: 10x10 halo for all 64 channels (zeros outside).
  for (int idx = t; idx < CH * 100; idx += 256) {
    int c = idx / 100;
    int rem = idx - c * 100;
    int yy = rem / 10;
    int xx = rem - yy * 10;
    int gy = ty0 - 1 + yy, gx = tx0 - 1 + xx;
    float v = 0.f;
    if (gy >= 0 && gy < H && gx >= 0 && gx < H)
      v = in[img_base + ((long)c * H + gy) * H + gx];
    s_in[c * 120 + yy * 12 + xx] = v;
  }
  __syncthreads();

  int px = t & 63;
  int pxx = px & 7, pxy = px >> 3;
  int w = wave_id();

  // Phase B: depthwise 3x3, result stored IN-PLACE at the (pxy,pxx) halo slot.
  // Safe within a wave: all 9 tap-reads issue (and land, lgkmcnt) before the write;
  // each channel is touched by exactly one wave; barrier before Phase C.
  #pragma unroll
  for (int k = 0; k < 16; ++k) {
    int c = w + 4 * k;
    const float* dwc = dww + ((long)depth * CH + c) * 9;
    const float* base = &s_in[c * 120 + pxy * 12 + pxx];
    float a = 0.f;
    #pragma unroll
    for (int dy = 0; dy < 3; ++dy)
      #pragma unroll
      for (int dx = 0; dx < 3; ++dx)
        a = fmaf(dwc[dy * 3 + dx], base[dy * 12 + dx], a);
    s_in[c * 120 + pxy * 12 + pxx] = a;
  }
  __syncthreads();

  // Phase C: pointwise 64->64; o = w*16+k; weights contiguous in o -> s_load_x16.
  const float* wc = wcT + ((subnet * NCD + depth) * CH) * CH + w * 16;
  float acc[16];
  #pragma unroll
  for (int k = 0; k < 16; ++k) acc[k] = 0.f;
  #pragma unroll 4
  for (int c = 0; c < CH; ++c) {
    float v = s_in[c * 120 + pxy * 12 + pxx];
    const float* wr = wc + c * CH;
    #pragma unroll
    for (int k = 0; k < 16; ++k)
      acc[k] = fmaf(wr[k], v, acc[k]);
  }

  int ox = tx0 + pxx, oy = ty0 + pxy;
  if (ox < H && oy < H) {
    float* outp = buf_out + (long)subnet * S + lvl_off(lvl) + img_base;
    int bno = (lvl * NCD + depth) * CH;
    #pragma unroll
    for (int k = 0; k < 16; ++k) {
      int o = w * 16 + k;
      float scale = bg[bno + o] * rsqrtf(bv[bno + o] + BNEPS);
      float z = fmaf(acc[k] + pwb[depth * CH + o] - bm[bno + o], scale, bb[bno + o]);
      float y = z / (1.f + __expf(-z));
      outp[((long)o * H + oy) * H + ox] = y;
    }
  }
}

// ---- heads' depthwise, output transposed: dv[subnet][c][flat_pixel] ----
__global__ __launch_bounds__(256) void head_dw_kernel(
    const float* __restrict__ buf_in, float* __restrict__ dv,
    const float* __restrict__ score_dw, const float* __restrict__ pred_dw)
{
  __shared__ float s_in[CH * 120];

  int bx = blockIdx.x;
  int subnet = bx / TPS;
  int r = bx - subnet * TPS;
  int n = r / TPI;
  int u = r - n * TPI;
  int lvl, tx0, ty0;
  decode_tile(u, lvl, tx0, ty0);
  int H = 64 >> lvl;

  const float* in = buf_in + (long)subnet * S + lvl_off(lvl);
  const float* dww = subnet ? pred_dw : score_dw;  // (C,1,3,3)
  float* dvs = dv + (long)subnet * S;

  int t = threadIdx.x;
  long img_base = (long)n * CH * H * H;

  for (int idx = t; idx < CH * 100; idx += 256) {
    int c = idx / 100;
    int rem = idx - c * 100;
    int yy = rem / 10;
    int xx = rem - yy * 10;
    int gy = ty0 - 1 + yy, gx = tx0 - 1 + xx;
    float v = 0.f;
    if (gy >= 0 && gy < H && gx >= 0 && gx < H)
      v = in[img_base + ((long)c * H + gy) * H + gx];
    s_in[c * 120 + yy * 12 + xx] = v;
  }
  __syncthreads();

  int px = t & 63;
  int pxx = px & 7, pxy = px >> 3;
  int w = wave_id();

  int ox = tx0 + pxx, oy = ty0 + pxy;
  bool valid = (ox < H) && (oy < H);
  int fp = lvl_lb(lvl) + n * H * H + oy * H + ox;

  #pragma unroll
  for (int k = 0; k < 16; ++k) {
    int c = w + 4 * k;
    const float* dwc = dww + c * 9;
    const float* base = &s_in[c * 120 + pxy * 12 + pxx];
    float a = 0.f;
    #pragma unroll
    for (int dy = 0; dy < 3; ++dy)
      #pragma unroll
      for (int dx = 0; dx < 3; ++dx)
        a = fmaf(dwc[dy * 3 + dx], base[dy * 12 + dx], a);
    if (valid) dvs[c * TOT + fp] = a;
  }
}

// ---- head GEMM: wave = 64 px (1/lane), dv[64] in regs, sweep 128-o chunk ----
// Jobs: score = 682 px-tiles x 7 chunks of 128 o (8 subtiles of 16);
//       pred  = 682 px-tiles x 1 chunk of 48 o (3 subtiles of 16).
__global__ __launch_bounds__(256) void head_gemm_kernel(
    const float* __restrict__ dv, const float* __restrict__ wT,
    const float* __restrict__ wpT,
    const float* __restrict__ score_b, const float* __restrict__ pred_b,
    float* __restrict__ out)
{
  int lane = threadIdx.x & 63;
  int wid = wave_id();
  int wj = blockIdx.x * 4 + wid;

  int subnet, pt, oc0, nsub;
  if (wj < NSJ) { subnet = 0; pt = wj / 7; oc0 = (wj - pt * 7) * 128; nsub = 8; }
  else          { subnet = 1; pt = wj - NSJ; oc0 = 0; nsub = 3; }

  int fp0 = pt * 64;
  int lvl, lb, lsh;
  if (fp0 < 32768)      { lvl = 0; lb = 0;     lsh = 12; }
  else if (fp0 < 40960) { lvl = 1; lb = 32768; lsh = 10; }
  else if (fp0 < 43008) { lvl = 2; lb = 40960; lsh = 8;  }
  else if (fp0 < 43520) { lvl = 3; lb = 43008; lsh = 6;  }
  else                  { lvl = 4; lb = 43520; lsh = 4;  }
  int HH = 1 << lsh;

  int OC = subnet ? 36 : 810;
  int wstr = subnet ? CH : WSTR_S;
  const float* wtab = subnet ? wpT : wT;
  const float* btab = subnet ? pred_b : score_b;

  // Load this lane's full depthwise vector into registers (coalesced, strided c).
  const float* dvp = dv + (long)subnet * S + fp0 + lane;
  float dvr[64];
  #pragma unroll
  for (int c = 0; c < CH; ++c) dvr[c] = dvp[c * TOT];

  int rem = fp0 + lane - lb;
  int n = rem >> lsh;
  int r2 = rem & (HH - 1);
  long pbase = head_out_base(subnet, lvl) + (long)n * OC * HH + r2;

  for (int s = 0; s < nsub; ++s) {
    int o0 = oc0 + s * 16;
    const float* wp = wtab + o0;
    float acc[16];
    #pragma unroll
    for (int k = 0; k < 16; ++k) acc[k] = 0.f;
    #pragma unroll 16
    for (int c = 0; c < CH; ++c) {
      const float* wr = wp + c * wstr;   // uniform addr -> s_load_dwordx16
      float v = dvr[c];
      #pragma unroll
      for (int k = 0; k < 16; ++k)
        acc[k] = fmaf(wr[k], v, acc[k]);
    }
    #pragma unroll
    for (int k = 0; k < 16; ++k) {
      int o = o0 + k;
      if (o < OC)
        __builtin_nontemporal_store(acc[k] + btab[o], &out[pbase + (long)o * HH]);
    }
  }
}

extern "C" void kernel_launch(void* const* d_in, const int* in_sizes, int n_in,
                              void* d_out, int out_size, void* d_ws, size_t ws_size,
                              hipStream_t stream) {
  const float* p3 = (const float*)d_in[0];
  const float* p4 = (const float*)d_in[1];
  const float* p5 = (const float*)d_in[2];
  const float* p6 = (const float*)d_in[3];
  const float* p7 = (const float*)d_in[4];
  const float* cls_dw = (const float*)d_in[5];
  const float* cls_pw = (const float*)d_in[6];
  const float* cls_pwb = (const float*)d_in[7];
  const float* box_dw = (const float*)d_in[8];
  const float* box_pw = (const float*)d_in[9];
  const float* box_pwb = (const float*)d_in[10];
  const float* bn_cls_g = (const float*)d_in[11];
  const float* bn_cls_b = (const float*)d_in[12];
  const float* bn_cls_m = (const float*)d_in[13];
  const float* bn_cls_v = (const float*)d_in[14];
  const float* bn_box_g = (const float*)d_in[15];
  const float* bn_box_b = (const float*)d_in[16];
  const float* bn_box_m = (const float*)d_in[17];
  const float* bn_box_v = (const float*)d_in[18];
  const float* score_dw = (const float*)d_in[19];
  const float* score_pw = (const float*)d_in[20];
  const float* score_b = (const float*)d_in[21];
  const float* pred_dw = (const float*)d_in[22];
  const float* pred_pw = (const float*)d_in[23];
  const float* pred_b = (const float*)d_in[24];

  float* ws = (float*)d_ws;
  float* out = (float*)d_out;
  float* buf0 = ws;
  float* buf1 = ws + 2 * S;
  float* dv = buf1;                 // dv[subnet][c][pixel], exactly 2*S floats
  float* wcT = out;                 // 24576 floats; overwritten by head_gemm later
  float* wT = ws;                   // score weights [64][896] (buf0 reuse, post head_dw)
  float* wpT = ws + CH * WSTR_S;    // pred weights [64][64]

  dim3 blk(256);
  prep_stage_kernel<<<dim3(96), blk, 0, stream>>>(cls_pw, box_pw, wcT);
  stage_kernel<<<dim3(2 * TPS), blk, 0, stream>>>(
      p3, p4, p5, p6, p7, nullptr, buf0, cls_dw, box_dw, wcT, cls_pwb, box_pwb,
      bn_cls_g, bn_cls_b, bn_cls_m, bn_cls_v,
      bn_box_g, bn_box_b, bn_box_m, bn_box_v, 0);
  stage_kernel<<<dim3(2 * TPS), blk, 0, stream>>>(
      p3, p4, p5, p6, p7, buf0, buf1, cls_dw, box_dw, wcT, cls_pwb, box_pwb,
      bn_cls_g, bn_cls_b, bn_cls_m, bn_cls_v,
      bn_box_g, bn_box_b, bn_box_m, bn_box_v, 1);
  stage_kernel<<<dim3(2 * TPS), blk, 0, stream>>>(
      p3, p4, p5, p6, p7, buf1, buf0, cls_dw, box_dw, wcT, cls_pwb, box_pwb,
      bn_cls_g, bn_cls_b, bn_cls_m, bn_cls_v,
      bn_box_g, bn_box_b, bn_box_m, bn_box_v, 2);
  head_dw_kernel<<<dim3(2 * TPS), blk, 0, stream>>>(buf0, dv, score_dw, pred_dw);
  prep_head_kernel<<<dim3(240), blk, 0, stream>>>(score_pw, pred_pw, wT, wpT);
  head_gemm_kernel<<<dim3(GEMM_BLOCKS), blk, 0, stream>>>(
      dv, wT, wpT, score_b, pred_b, out);
}

// Round 9
// 497.478 us; speedup vs baseline: 1.4762x; 1.1150x over previous
//
#include <hip/hip_runtime.h>

// EfficientDet head, fp32. 7 launches:
//   prep_stage:  transpose cls/box pointwise weights to [d][c][o]  (stored in d_out head)
//   stage x3:    dw3x3(in-place LDS) + pw(64x64, s_load_x16 weights) + BN + swish
//   head_dw:     heads' depthwise, written transposed dv[c][pixel]
//   prep_head:   transpose score/pred pointwise weights to [c][o] (padded to 896/64)
//   head_gemm:   register GEMM v2 — dv[64] forced into VGPRs (__launch_bounds__ cap),
//                px-chunk x 9-subjob decomposition, bijective XCD swizzle so all
//                subjobs sharing a dv tile hit the same XCD L2, plain (non-NT) stores.
//
// ws layout (floats), exactly 4*S (proven size):
//   [0, 2S)   buf0 (stage ping A); head wT/wpT tables overwrite after head_dw consumes
//   [2S, 4S)  buf1 (stage ping B); reused as dv[subnet][c][pixel] (exactly fits)
// wcT (stage pw weights, 24576 floats) lives at d_out[0..24576) — consumed by the
// stages, then fully overwritten by head_gemm.

namespace {
constexpr int CH = 64;
constexpr int NCD = 3;
constexpr long S = 2793472;        // floats per subnet activation buffer
constexpr int TPI = 86;            // tiles per image (64+16+4+1+1)
constexpr int TPS = 688;           // tiles per subnet (86*8)
constexpr int TOT = 43648;         // total pixels per (subnet, channel)
constexpr float BNEPS = 1e-3f;
constexpr int WSTR_S = 896;        // padded score weight row
// head_gemm v2 geometry: 171 px-chunks of 256 px; 9 subjobs per chunk
// (8 score o-groups of 112 o + 1 pred). All 9 share the chunk's dv tile.
constexpr int NCHUNK = 171;        // ceil(43648/256); last chunk has 128 px
constexpr int GEMM_BLOCKS = NCHUNK * 9;       // 1539
constexpr int QXC = GEMM_BLOCKS / 8;          // 192
constexpr int RXC = GEMM_BLOCKS - 8 * QXC;    // 3
}

__device__ __forceinline__ int wave_id() {
  return __builtin_amdgcn_readfirstlane((int)(threadIdx.x >> 6));
}

__device__ __forceinline__ void decode_tile(int u, int& lvl, int& tx0, int& ty0) {
  int tile, tpr;
  if (u < 64)       { lvl = 0; tile = u;      tpr = 8; }
  else if (u < 80)  { lvl = 1; tile = u - 64; tpr = 4; }
  else if (u < 84)  { lvl = 2; tile = u - 80; tpr = 2; }
  else if (u == 84) { lvl = 3; tile = 0;      tpr = 1; }
  else              { lvl = 4; tile = 0;      tpr = 1; }
  tx0 = (tile % tpr) * 8;
  ty0 = (tile / tpr) * 8;
}

__device__ __forceinline__ long lvl_off(int lvl) {  // into [c][H][W] level-packed subnet buf
  switch (lvl) {
    case 0: return 0L;
    case 1: return 2097152L;
    case 2: return 2621440L;
    case 3: return 2752512L;
    default: return 2785280L;
  }
}

__device__ __forceinline__ int lvl_lb(int lvl) {    // pixel-flat level base
  switch (lvl) {
    case 0: return 0;
    case 1: return 32768;
    case 2: return 40960;
    case 3: return 43008;
    default: return 43520;
  }
}

__device__ __forceinline__ long head_out_base(int subnet, int lvl) {
  if (subnet == 0) {
    switch (lvl) {
      case 0: return 0L;
      case 1: return 26542080L;
      case 2: return 33177600L;
      case 3: return 34836480L;
      default: return 35251200L;
    }
  } else {
    switch (lvl) {
      case 0: return 35354880L;
      case 1: return 36534528L;
      case 2: return 36829440L;
      case 3: return 36903168L;
      default: return 36921600L;
    }
  }
}

// ---- prep: stage pointwise weights (NC,o,c) -> wcT[(subnet*3+d)*64+c][o] ----
__global__ __launch_bounds__(256) void prep_stage_kernel(
    const float* __restrict__ cls_pw, const float* __restrict__ box_pw,
    float* __restrict__ wcT) {
  int i = blockIdx.x * 256 + threadIdx.x;
  if (i >= 2 * NCD * CH * CH) return;
  int o = i & 63;
  int c = (i >> 6) & 63;
  int sd = i >> 12;                       // subnet*3 + d
  const float* src = (sd < NCD) ? cls_pw : box_pw;
  int d = (sd < NCD) ? sd : sd - NCD;
  wcT[i] = src[(d * CH + o) * CH + c];
}

// ---- prep: head pw weights -> wT[c][896] (score, zero-padded), wpT[c][64] (pred) ----
__global__ __launch_bounds__(256) void prep_head_kernel(
    const float* __restrict__ score_pw, const float* __restrict__ pred_pw,
    float* __restrict__ wT, float* __restrict__ wpT) {
  int i = blockIdx.x * 256 + threadIdx.x;
  if (i < CH * WSTR_S) {
    int c = i / WSTR_S;
    int o = i - c * WSTR_S;
    wT[i] = (o < 810) ? score_pw[o * CH + c] : 0.f;
  } else {
    int j = i - CH * WSTR_S;
    if (j < CH * CH) {
      int c = j >> 6;
      int o = j & 63;
      wpT[j] = (o < 36) ? pred_pw[o * CH + c] : 0.f;
    }
  }
}

// ---- subnet stage: dw3x3 + pw64x64 + bias + BN + swish ----
__global__ __launch_bounds__(256) void stage_kernel(
    const float* __restrict__ q0, const float* __restrict__ q1,
    const float* __restrict__ q2, const float* __restrict__ q3,
    const float* __restrict__ q4,
    const float* __restrict__ buf_in, float* __restrict__ buf_out,
    const float* __restrict__ cls_dw, const float* __restrict__ box_dw,
    const float* __restrict__ wcT,
    const float* __restrict__ cls_pwb, const float* __restrict__ box_pwb,
    const float* __restrict__ bng0, const float* __restrict__ bnb0,
    const float* __restrict__ bnm0, const float* __restrict__ bnv0,
    const float* __restrict__ bng1, const float* __restrict__ bnb1,
    const float* __restrict__ bnm1, const float* __restrict__ bnv1,
    int depth)
{
  __shared__ float s_in[CH * 120];   // [c][10 rows][pitch 12]; dw result overwrites in place

  int bx = blockIdx.x;
  int subnet = bx / TPS;
  int r = bx - subnet * TPS;
  int n = r / TPI;
  int u = r - n * TPI;
  int lvl, tx0, ty0;
  decode_tile(u, lvl, tx0, ty0);
  int H = 64 >> lvl;

  const float* in;
  if (depth == 0) {
    in = (lvl == 0) ? q0 : (lvl == 1) ? q1 : (lvl == 2) ? q2 : (lvl == 3) ? q3 : q4;
  } else {
    in = buf_in + (long)subnet * S + lvl_off(lvl);
  }
  const float* dww = subnet ? box_dw : cls_dw;    // (NC,C,9)
  const float* pwb = subnet ? box_pwb : cls_pwb;  // (NC,C)
  const float* bg = subnet ? bng1 : bng0;         // (NL,NC,C)
  const float* bb = subnet ? bnb1 : bnb0;
  const float* bm = subnet ? bnm1 : bnm0;
  const float* bv = subnet ? bnv1 : bnv0;

  int t = threadIdx.x;
  long img_base = (long)n * CH * H * H;

  // Phase A: 10x10 halo for all 64 channels (zeros outside).
  for (int idx = t; idx < CH * 100; idx += 256) {
    int c = idx / 100;
    int rem = idx - c * 100;
    int yy = rem / 10;
    int xx = rem - yy * 10;
    int gy = ty0 - 1 + yy, gx = tx0 - 1 + xx;
    float v = 0.f;
    if (gy >= 0 && gy < H && gx >= 0 && gx < H)
      v = in[img_base + ((long)c * H + gy) * H + gx];
    s_in[c * 120 + yy * 12 + xx] = v;
  }
  __syncthreads();

  int px = t & 63;
  int pxx = px & 7, pxy = px >> 3;
  int w = wave_id();

  // Phase B: depthwise 3x3, result stored IN-PLACE at the (pxy,pxx) halo slot.
  // Safe within a wave: all 9 tap-reads issue (and land, lgkmcnt) before the write;
  // each channel is touched by exactly one wave; barrier before Phase C.
  #pragma unroll
  for (int k = 0; k < 16; ++k) {
    int c = w + 4 * k;
    const float* dwc = dww + ((long)depth * CH + c) * 9;
    const float* base = &s_in[c * 120 + pxy * 12 + pxx];
    float a = 0.f;
    #pragma unroll
    for (int dy = 0; dy < 3; ++dy)
      #pragma unroll
      for (int dx = 0; dx < 3; ++dx)
        a = fmaf(dwc[dy * 3 + dx], base[dy * 12 + dx], a);
    s_in[c * 120 + pxy * 12 + pxx] = a;
  }
  __syncthreads();

  // Phase C: pointwise 64->64; o = w*16+k; weights contiguous in o -> s_load_x16.
  const float* wc = wcT + ((subnet * NCD + depth) * CH) * CH + w * 16;
  float acc[16];
  #pragma unroll
  for (int k = 0; k < 16; ++k) acc[k] = 0.f;
  #pragma unroll 4
  for (int c = 0; c < CH; ++c) {
    float v = s_in[c * 120 + pxy * 12 + pxx];
    const float* wr = wc + c * CH;
    #pragma unroll
    for (int k = 0; k < 16; ++k)
      acc[k] = fmaf(wr[k], v, acc[k]);
  }

  int ox = tx0 + pxx, oy = ty0 + pxy;
  if (ox < H && oy < H) {
    float* outp = buf_out + (long)subnet * S + lvl_off(lvl) + img_base;
    int bno = (lvl * NCD + depth) * CH;
    #pragma unroll
    for (int k = 0; k < 16; ++k) {
      int o = w * 16 + k;
      float scale = bg[bno + o] * rsqrtf(bv[bno + o] + BNEPS);
      float z = fmaf(acc[k] + pwb[depth * CH + o] - bm[bno + o], scale, bb[bno + o]);
      float y = z / (1.f + __expf(-z));
      outp[((long)o * H + oy) * H + ox] = y;
    }
  }
}

// ---- heads' depthwise, output transposed: dv[subnet][c][flat_pixel] ----
__global__ __launch_bounds__(256) void head_dw_kernel(
    const float* __restrict__ buf_in, float* __restrict__ dv,
    const float* __restrict__ score_dw, const float* __restrict__ pred_dw)
{
  __shared__ float s_in[CH * 120];

  int bx = blockIdx.x;
  int subnet = bx / TPS;
  int r = bx - subnet * TPS;
  int n = r / TPI;
  int u = r - n * TPI;
  int lvl, tx0, ty0;
  decode_tile(u, lvl, tx0, ty0);
  int H = 64 >> lvl;

  const float* in = buf_in + (long)subnet * S + lvl_off(lvl);
  const float* dww = subnet ? pred_dw : score_dw;  // (C,1,3,3)
  float* dvs = dv + (long)subnet * S;

  int t = threadIdx.x;
  long img_base = (long)n * CH * H * H;

  for (int idx = t; idx < CH * 100; idx += 256) {
    int c = idx / 100;
    int rem = idx - c * 100;
    int yy = rem / 10;
    int xx = rem - yy * 10;
    int gy = ty0 - 1 + yy, gx = tx0 - 1 + xx;
    float v = 0.f;
    if (gy >= 0 && gy < H && gx >= 0 && gx < H)
      v = in[img_base + ((long)c * H + gy) * H + gx];
    s_in[c * 120 + yy * 12 + xx] = v;
  }
  __syncthreads();

  int px = t & 63;
  int pxx = px & 7, pxy = px >> 3;
  int w = wave_id();

  int ox = tx0 + pxx, oy = ty0 + pxy;
  bool valid = (ox < H) && (oy < H);
  int fp = lvl_lb(lvl) + n * H * H + oy * H + ox;

  #pragma unroll
  for (int k = 0; k < 16; ++k) {
    int c = w + 4 * k;
    const float* dwc = dww + c * 9;
    const float* base = &s_in[c * 120 + pxy * 12 + pxx];
    float a = 0.f;
    #pragma unroll
    for (int dy = 0; dy < 3; ++dy)
      #pragma unroll
      for (int dx = 0; dx < 3; ++dx)
        a = fmaf(dwc[dy * 3 + dx], base[dy * 12 + dx], a);
    if (valid) dvs[c * TOT + fp] = a;
  }
}

// ---- head GEMM v2 ----
// Job j = pxc*9 + sub; pxc = 256-px chunk; sub 0..7 = score o-group (112 o each,
// 7 subtiles of 16), sub 8 = pred (48 o, 3 subtiles). Wave w of a block owns
// px fp0 = pxc*256 + w*64 with dv[64] in registers (launch_bounds caps occupancy
// so the tile stays register-resident). blockIdx -> job via bijective XCD swizzle:
// consecutive jobs (sharing a dv tile) land on the same XCD's L2.
__global__ __launch_bounds__(256, 4) void head_gemm_kernel(
    const float* __restrict__ dv, const float* __restrict__ wT,
    const float* __restrict__ wpT,
    const float* __restrict__ score_b, const float* __restrict__ pred_b,
    float* __restrict__ out)
{
  int lane = threadIdx.x & 63;
  int wid = wave_id();

  int b = blockIdx.x;
  int xk = b & 7, xi = b >> 3;
  int job = (xk < RXC) ? xk * (QXC + 1) + xi
                       : RXC * (QXC + 1) + (xk - RXC) * QXC + xi;
  int pxc = job / 9;
  int sub = job - pxc * 9;

  int fp0 = pxc * 256 + wid * 64;
  if (fp0 >= TOT) return;            // last chunk has only 128 px; no barriers below

  int subnet = (sub == 8) ? 1 : 0;

  int lvl, lb, lsh;
  if (fp0 < 32768)      { lvl = 0; lb = 0;     lsh = 12; }
  else if (fp0 < 40960) { lvl = 1; lb = 32768; lsh = 10; }
  else if (fp0 < 43008) { lvl = 2; lb = 40960; lsh = 8;  }
  else if (fp0 < 43520) { lvl = 3; lb = 43008; lsh = 6;  }
  else                  { lvl = 4; lb = 43520; lsh = 4;  }
  int HH = 1 << lsh;

  int OC = subnet ? 36 : 810;
  int wstr = subnet ? CH : WSTR_S;
  const float* wtab = subnet ? wpT : wT;
  const float* btab = subnet ? pred_b : score_b;

  // Register-resident dv tile for this wave's 64 px (coalesced 256B per c).
  const float* dvp = dv + (long)subnet * S + fp0 + lane;
  float dvr[64];
  #pragma unroll
  for (int c = 0; c < CH; ++c) dvr[c] = dvp[c * TOT];

  int rem = fp0 + lane - lb;
  int n = rem >> lsh;
  int r2 = rem & (HH - 1);
  long pbase = head_out_base(subnet, lvl) + (long)n * OC * HH + r2;

  int o_begin = subnet ? 0 : sub * 112;
  int o_end = subnet ? 48 : (sub * 112 + 112 < 832 ? sub * 112 + 112 : 832);

  for (int o0 = o_begin; o0 < o_end; o0 += 16) {
    const float* wp = wtab + o0;
    float acc[16];
    #pragma unroll
    for (int k = 0; k < 16; ++k) acc[k] = 0.f;
    #pragma unroll 8
    for (int c = 0; c < CH; ++c) {
      const float* wr = wp + c * wstr;   // uniform addr -> s_load_dwordx16
      float v = dvr[c];
      #pragma unroll
      for (int k = 0; k < 16; ++k)
        acc[k] = fmaf(wr[k], v, acc[k]);
    }
    #pragma unroll
    for (int k = 0; k < 16; ++k) {
      int o = o0 + k;
      if (o < OC)
        out[pbase + (long)o * HH] = acc[k] + btab[o];
    }
  }
}

extern "C" void kernel_launch(void* const* d_in, const int* in_sizes, int n_in,
                              void* d_out, int out_size, void* d_ws, size_t ws_size,
                              hipStream_t stream) {
  const float* p3 = (const float*)d_in[0];
  const float* p4 = (const float*)d_in[1];
  const float* p5 = (const float*)d_in[2];
  const float* p6 = (const float*)d_in[3];
  const float* p7 = (const float*)d_in[4];
  const float* cls_dw = (const float*)d_in[5];
  const float* cls_pw = (const float*)d_in[6];
  const float* cls_pwb = (const float*)d_in[7];
  const float* box_dw = (const float*)d_in[8];
  const float* box_pw = (const float*)d_in[9];
  const float* box_pwb = (const float*)d_in[10];
  const float* bn_cls_g = (const float*)d_in[11];
  const float* bn_cls_b = (const float*)d_in[12];
  const float* bn_cls_m = (const float*)d_in[13];
  const float* bn_cls_v = (const float*)d_in[14];
  const float* bn_box_g = (const float*)d_in[15];
  const float* bn_box_b = (const float*)d_in[16];
  const float* bn_box_m = (const float*)d_in[17];
  const float* bn_box_v = (const float*)d_in[18];
  const float* score_dw = (const float*)d_in[19];
  const float* score_pw = (const float*)d_in[20];
  const float* score_b = (const float*)d_in[21];
  const float* pred_dw = (const float*)d_in[22];
  const float* pred_pw = (const float*)d_in[23];
  const float* pred_b = (const float*)d_in[24];

  float* ws = (float*)d_ws;
  float* out = (float*)d_out;
  float* buf0 = ws;
  float* buf1 = ws + 2 * S;
  float* dv = buf1;                 // dv[subnet][c][pixel], exactly 2*S floats
  float* wcT = out;                 // 24576 floats; overwritten by head_gemm later
  float* wT = ws;                   // score weights [64][896] (buf0 reuse, post head_dw)
  float* wpT = ws + CH * WSTR_S;    // pred weights [64][64]

  dim3 blk(256);
  prep_stage_kernel<<<dim3(96), blk, 0, stream>>>(cls_pw, box_pw, wcT);
  stage_kernel<<<dim3(2 * TPS), blk, 0, stream>>>(
      p3, p4, p5, p6, p7, nullptr, buf0, cls_dw, box_dw, wcT, cls_pwb, box_pwb,
      bn_cls_g, bn_cls_b, bn_cls_m, bn_cls_v,
      bn_box_g, bn_box_b, bn_box_m, bn_box_v, 0);
  stage_kernel<<<dim3(2 * TPS), blk, 0, stream>>>(
      p3, p4, p5, p6, p7, buf0, buf1, cls_dw, box_dw, wcT, cls_pwb, box_pwb,
      bn_cls_g, bn_cls_b, bn_cls_m, bn_cls_v,
      bn_box_g, bn_box_b, bn_box_m, bn_box_v, 1);
  stage_kernel<<<dim3(2 * TPS), blk, 0, stream>>>(
      p3, p4, p5, p6, p7, buf1, buf0, cls_dw, box_dw, wcT, cls_pwb, box_pwb,
      bn_cls_g, bn_cls_b, bn_cls_m, bn_cls_v,
      bn_box_g, bn_box_b, bn_box_m, bn_box_v, 2);
  head_dw_kernel<<<dim3(2 * TPS), blk, 0, stream>>>(buf0, dv, score_dw, pred_dw);
  prep_head_kernel<<<dim3(240), blk, 0, stream>>>(score_pw, pred_pw, wT, wpT);
  head_gemm_kernel<<<dim3(GEMM_BLOCKS), blk, 0, stream>>>(
      dv, wT, wpT, score_b, pred_b, out);
}

// Round 10
// 430.462 us; speedup vs baseline: 1.7060x; 1.1557x over previous
//
#include <hip/hip_runtime.h>

// EfficientDet head, fp32. 7 launches:
//   prep_stage:  transpose cls/box pointwise weights to [d][c][o]  (stored in d_out head)
//   stage x3:    dw3x3(in-place LDS) + pw(64x64, s_load_x16 weights) + BN + swish
//   head_dw:     heads' depthwise, written transposed dv[c][pixel]
//   prep_head:   transpose score/pred pointwise weights to [c][o] (padded to 896/64)
//   head_gemm:   v3 — dv tile staged in LDS (16KB/block, residency is structural,
//                not a register-allocator gamble); block = 64px x 4 o-subtile waves;
//                bijective XCD swizzle keeps a tile's 14 sub-blocks on one XCD L2.
//
// ws layout (floats), exactly 4*S (proven size):
//   [0, 2S)   buf0 (stage ping A); head wT/wpT tables overwrite after head_dw consumes
//   [2S, 4S)  buf1 (stage ping B); reused as dv[subnet][c][pixel] (exactly fits)
// wcT (stage pw weights, 24576 floats) lives at d_out[0..24576) — consumed by the
// stages, then fully overwritten by head_gemm.

namespace {
constexpr int CH = 64;
constexpr int NCD = 3;
constexpr long S = 2793472;        // floats per subnet activation buffer
constexpr int TPI = 86;            // tiles per image (64+16+4+1+1)
constexpr int TPS = 688;           // tiles per subnet (86*8)
constexpr int TOT = 43648;         // total pixels per (subnet, channel)
constexpr float BNEPS = 1e-3f;
constexpr int WSTR_S = 896;        // padded score weight row
// head_gemm v3 geometry: 682 px-tiles of 64; per tile 14 sub-blocks:
// sb 0..12 = score (4 waves x 16-o subtiles, 51 subtiles total, tail idle),
// sb 13    = pred  (3 subtiles + 1 idle wave).
constexpr int NSB = 14;
constexpr int GEMM_BLOCKS = 682 * NSB;        // 9548
constexpr int QXC = GEMM_BLOCKS / 8;          // 1193
constexpr int RXC = GEMM_BLOCKS - 8 * QXC;    // 4
}

__device__ __forceinline__ int wave_id() {
  return __builtin_amdgcn_readfirstlane((int)(threadIdx.x >> 6));
}

__device__ __forceinline__ void decode_tile(int u, int& lvl, int& tx0, int& ty0) {
  int tile, tpr;
  if (u < 64)       { lvl = 0; tile = u;      tpr = 8; }
  else if (u < 80)  { lvl = 1; tile = u - 64; tpr = 4; }
  else if (u < 84)  { lvl = 2; tile = u - 80; tpr = 2; }
  else if (u == 84) { lvl = 3; tile = 0;      tpr = 1; }
  else              { lvl = 4; tile = 0;      tpr = 1; }
  tx0 = (tile % tpr) * 8;
  ty0 = (tile / tpr) * 8;
}

__device__ __forceinline__ long lvl_off(int lvl) {  // into [c][H][W] level-packed subnet buf
  switch (lvl) {
    case 0: return 0L;
    case 1: return 2097152L;
    case 2: return 2621440L;
    case 3: return 2752512L;
    default: return 2785280L;
  }
}

__device__ __forceinline__ int lvl_lb(int lvl) {    // pixel-flat level base
  switch (lvl) {
    case 0: return 0;
    case 1: return 32768;
    case 2: return 40960;
    case 3: return 43008;
    default: return 43520;
  }
}

__device__ __forceinline__ long head_out_base(int subnet, int lvl) {
  if (subnet == 0) {
    switch (lvl) {
      case 0: return 0L;
      case 1: return 26542080L;
      case 2: return 33177600L;
      case 3: return 34836480L;
      default: return 35251200L;
    }
  } else {
    switch (lvl) {
      case 0: return 35354880L;
      case 1: return 36534528L;
      case 2: return 36829440L;
      case 3: return 36903168L;
      default: return 36921600L;
    }
  }
}

// ---- prep: stage pointwise weights (NC,o,c) -> wcT[(subnet*3+d)*64+c][o] ----
__global__ __launch_bounds__(256) void prep_stage_kernel(
    const float* __restrict__ cls_pw, const float* __restrict__ box_pw,
    float* __restrict__ wcT) {
  int i = blockIdx.x * 256 + threadIdx.x;
  if (i >= 2 * NCD * CH * CH) return;
  int o = i & 63;
  int c = (i >> 6) & 63;
  int sd = i >> 12;                       // subnet*3 + d
  const float* src = (sd < NCD) ? cls_pw : box_pw;
  int d = (sd < NCD) ? sd : sd - NCD;
  wcT[i] = src[(d * CH + o) * CH + c];
}

// ---- prep: head pw weights -> wT[c][896] (score, zero-padded), wpT[c][64] (pred) ----
__global__ __launch_bounds__(256) void prep_head_kernel(
    const float* __restrict__ score_pw, const float* __restrict__ pred_pw,
    float* __restrict__ wT, float* __restrict__ wpT) {
  int i = blockIdx.x * 256 + threadIdx.x;
  if (i < CH * WSTR_S) {
    int c = i / WSTR_S;
    int o = i - c * WSTR_S;
    wT[i] = (o < 810) ? score_pw[o * CH + c] : 0.f;
  } else {
    int j = i - CH * WSTR_S;
    if (j < CH * CH) {
      int c = j >> 6;
      int o = j & 63;
      wpT[j] = (o < 36) ? pred_pw[o * CH + c] : 0.f;
    }
  }
}

// ---- subnet stage: dw3x3 + pw64x64 + bias + BN + swish ----
__global__ __launch_bounds__(256) void stage_kernel(
    const float* __restrict__ q0, const float* __restrict__ q1,
    const float* __restrict__ q2, const float* __restrict__ q3,
    const float* __restrict__ q4,
    const float* __restrict__ buf_in, float* __restrict__ buf_out,
    const float* __restrict__ cls_dw, const float* __restrict__ box_dw,
    const float* __restrict__ wcT,
    const float* __restrict__ cls_pwb, const float* __restrict__ box_pwb,
    const float* __restrict__ bng0, const float* __restrict__ bnb0,
    const float* __restrict__ bnm0, const float* __restrict__ bnv0,
    const float* __restrict__ bng1, const float* __restrict__ bnb1,
    const float* __restrict__ bnm1, const float* __restrict__ bnv1,
    int depth)
{
  __shared__ float s_in[CH * 120];   // [c][10 rows][pitch 12]; dw result overwrites in place

  int bx = blockIdx.x;
  int subnet = bx / TPS;
  int r = bx - subnet * TPS;
  int n = r / TPI;
  int u = r - n * TPI;
  int lvl, tx0, ty0;
  decode_tile(u, lvl, tx0, ty0);
  int H = 64 >> lvl;

  const float* in;
  if (depth == 0) {
    in = (lvl == 0) ? q0 : (lvl == 1) ? q1 : (lvl == 2) ? q2 : (lvl == 3) ? q3 : q4;
  } else {
    in = buf_in + (long)subnet * S + lvl_off(lvl);
  }
  const float* dww = subnet ? box_dw : cls_dw;    // (NC,C,9)
  const float* pwb = subnet ? box_pwb : cls_pwb;  // (NC,C)
  const float* bg = subnet ? bng1 : bng0;         // (NL,NC,C)
  const float* bb = subnet ? bnb1 : bnb0;
  const float* bm = subnet ? bnm1 : bnm0;
  const float* bv = subnet ? bnv1 : bnv0;

  int t = threadIdx.x;
  long img_base = (long)n * CH * H * H;

  // Phase A: 10x10 halo for all 64 channels (zeros outside).
  for (int idx = t; idx < CH * 100; idx += 256) {
    int c = idx / 100;
    int rem = idx - c * 100;
    int yy = rem / 10;
    int xx = rem - yy * 10;
    int gy = ty0 - 1 + yy, gx = tx0 - 1 + xx;
    float v = 0.f;
    if (gy >= 0 && gy < H && gx >= 0 && gx < H)
      v = in[img_base + ((long)c * H + gy) * H + gx];
    s_in[c * 120 + yy * 12 + xx] = v;
  }
  __syncthreads();

  int px = t & 63;
  int pxx = px & 7, pxy = px >> 3;
  int w = wave_id();

  // Phase B: depthwise 3x3, result stored IN-PLACE at the (pxy,pxx) halo slot.
  // Safe within a wave: all 9 tap-reads issue (and land, lgkmcnt) before the write;
  // each channel is touched by exactly one wave; barrier before Phase C.
  #pragma unroll
  for (int k = 0; k < 16; ++k) {
    int c = w + 4 * k;
    const float* dwc = dww + ((long)depth * CH + c) * 9;
    const float* base = &s_in[c * 120 + pxy * 12 + pxx];
    float a = 0.f;
    #pragma unroll
    for (int dy = 0; dy < 3; ++dy)
      #pragma unroll
      for (int dx = 0; dx < 3; ++dx)
        a = fmaf(dwc[dy * 3 + dx], base[dy * 12 + dx], a);
    s_in[c * 120 + pxy * 12 + pxx] = a;
  }
  __syncthreads();

  // Phase C: pointwise 64->64; o = w*16+k; weights contiguous in o -> s_load_x16.
  const float* wc = wcT + ((subnet * NCD + depth) * CH) * CH + w * 16;
  float acc[16];
  #pragma unroll
  for (int k = 0; k < 16; ++k) acc[k] = 0.f;
  #pragma unroll 4
  for (int c = 0; c < CH; ++c) {
    float v = s_in[c * 120 + pxy * 12 + pxx];
    const float* wr = wc + c * CH;
    #pragma unroll
    for (int k = 0; k < 16; ++k)
      acc[k] = fmaf(wr[k], v, acc[k]);
  }

  int ox = tx0 + pxx, oy = ty0 + pxy;
  if (ox < H && oy < H) {
    float* outp = buf_out + (long)subnet * S + lvl_off(lvl) + img_base;
    int bno = (lvl * NCD + depth) * CH;
    #pragma unroll
    for (int k = 0; k < 16; ++k) {
      int o = w * 16 + k;
      float scale = bg[bno + o] * rsqrtf(bv[bno + o] + BNEPS);
      float z = fmaf(acc[k] + pwb[depth * CH + o] - bm[bno + o], scale, bb[bno + o]);
      float y = z / (1.f + __expf(-z));
      outp[((long)o * H + oy) * H + ox] = y;
    }
  }
}

// ---- heads' depthwise, output transposed: dv[subnet][c][flat_pixel] ----
__global__ __launch_bounds__(256) void head_dw_kernel(
    const float* __restrict__ buf_in, float* __restrict__ dv,
    const float* __restrict__ score_dw, const float* __restrict__ pred_dw)
{
  __shared__ float s_in[CH * 120];

  int bx = blockIdx.x;
  int subnet = bx / TPS;
  int r = bx - subnet * TPS;
  int n = r / TPI;
  int u = r - n * TPI;
  int lvl, tx0, ty0;
  decode_tile(u, lvl, tx0, ty0);
  int H = 64 >> lvl;

  const float* in = buf_in + (long)subnet * S + lvl_off(lvl);
  const float* dww = subnet ? pred_dw : score_dw;  // (C,1,3,3)
  float* dvs = dv + (long)subnet * S;

  int t = threadIdx.x;
  long img_base = (long)n * CH * H * H;

  for (int idx = t; idx < CH * 100; idx += 256) {
    int c = idx / 100;
    int rem = idx - c * 100;
    int yy = rem / 10;
    int xx = rem - yy * 10;
    int gy = ty0 - 1 + yy, gx = tx0 - 1 + xx;
    float v = 0.f;
    if (gy >= 0 && gy < H && gx >= 0 && gx < H)
      v = in[img_base + ((long)c * H + gy) * H + gx];
    s_in[c * 120 + yy * 12 + xx] = v;
  }
  __syncthreads();

  int px = t & 63;
  int pxx = px & 7, pxy = px >> 3;
  int w = wave_id();

  int ox = tx0 + pxx, oy = ty0 + pxy;
  bool valid = (ox < H) && (oy < H);
  int fp = lvl_lb(lvl) + n * H * H + oy * H + ox;

  #pragma unroll
  for (int k = 0; k < 16; ++k) {
    int c = w + 4 * k;
    const float* dwc = dww + c * 9;
    const float* base = &s_in[c * 120 + pxy * 12 + pxx];
    float a = 0.f;
    #pragma unroll
    for (int dy = 0; dy < 3; ++dy)
      #pragma unroll
      for (int dx = 0; dx < 3; ++dx)
        a = fmaf(dwc[dy * 3 + dx], base[dy * 12 + dx], a);
    if (valid) dvs[c * TOT + fp] = a;
  }
}

// ---- head GEMM v3: LDS-staged dv tile, 4 o-subtile waves per block ----
// Block = one 64-px tile x one sub-block sb. All 256 threads stage the tile's
// dv slab [64c][64px] (16KB) to LDS, then wave w computes o-subtile:
//   sb<13: score subtile sb*4+w (o0 = 16*st), idle if >=51;  sb=13: pred subtile w (<3).
// Per c: conflict-free LDS read + 16 FMA with s_load_x16 weights. No register gamble.
__global__ __launch_bounds__(256) void head_gemm_kernel(
    const float* __restrict__ dv, const float* __restrict__ wT,
    const float* __restrict__ wpT,
    const float* __restrict__ score_b, const float* __restrict__ pred_b,
    float* __restrict__ out)
{
  __shared__ float s_dv[CH * 64];    // [c][px]

  int b = blockIdx.x;
  int xcd = b & 7, xi = b >> 3;
  int job = (xcd < RXC) ? xcd * (QXC + 1) + xi
                        : RXC * (QXC + 1) + (xcd - RXC) * QXC + xi;
  int pxt = job / NSB;
  int sb = job - pxt * NSB;
  int subnet = (sb == NSB - 1) ? 1 : 0;

  int fp0 = pxt * 64;
  int t = threadIdx.x;

  // Stage dv tile: per 4-c group, 4x 256B coalesced global reads; LDS writes
  // consecutive (conflict-free).
  const float* dvs = dv + (long)subnet * S + fp0;
  for (int idx = t; idx < CH * 64; idx += 256) {
    int c = idx >> 6;
    int px = idx & 63;
    s_dv[idx] = dvs[(long)c * TOT + px];
  }
  __syncthreads();

  int lane = t & 63;
  int wid = wave_id();

  int st;
  if (subnet == 0) { st = sb * 4 + wid; if (st >= 51) return; }
  else             { st = wid;          if (st >= 3)  return; }
  int o0 = st * 16;

  int lvl, lb, lsh;
  if (fp0 < 32768)      { lvl = 0; lb = 0;     lsh = 12; }
  else if (fp0 < 40960) { lvl = 1; lb = 32768; lsh = 10; }
  else if (fp0 < 43008) { lvl = 2; lb = 40960; lsh = 8;  }
  else if (fp0 < 43520) { lvl = 3; lb = 43008; lsh = 6;  }
  else                  { lvl = 4; lb = 43520; lsh = 4;  }
  int HH = 1 << lsh;

  int OC = subnet ? 36 : 810;
  int wstr = subnet ? CH : WSTR_S;
  const float* wtab = subnet ? wpT : wT;
  const float* btab = subnet ? pred_b : score_b;

  float acc[16];
  #pragma unroll
  for (int k = 0; k < 16; ++k) acc[k] = 0.f;
  const float* wp = wtab + o0;
  #pragma unroll 8
  for (int c = 0; c < CH; ++c) {
    float v = s_dv[c * 64 + lane];     // stride-1 across lanes: conflict-free
    const float* wr = wp + c * wstr;   // uniform addr -> s_load_dwordx16
    #pragma unroll
    for (int k = 0; k < 16; ++k)
      acc[k] = fmaf(wr[k], v, acc[k]);
  }

  int rem = fp0 + lane - lb;
  int n = rem >> lsh;
  int r2 = rem & (HH - 1);
  long pbase = head_out_base(subnet, lvl) + (long)n * OC * HH + r2;

  #pragma unroll
  for (int k = 0; k < 16; ++k) {
    int o = o0 + k;
    if (o < OC)
      out[pbase + (long)o * HH] = acc[k] + btab[o];
  }
}

extern "C" void kernel_launch(void* const* d_in, const int* in_sizes, int n_in,
                              void* d_out, int out_size, void* d_ws, size_t ws_size,
                              hipStream_t stream) {
  const float* p3 = (const float*)d_in[0];
  const float* p4 = (const float*)d_in[1];
  const float* p5 = (const float*)d_in[2];
  const float* p6 = (const float*)d_in[3];
  const float* p7 = (const float*)d_in[4];
  const float* cls_dw = (const float*)d_in[5];
  const float* cls_pw = (const float*)d_in[6];
  const float* cls_pwb = (const float*)d_in[7];
  const float* box_dw = (const float*)d_in[8];
  const float* box_pw = (const float*)d_in[9];
  const float* box_pwb = (const float*)d_in[10];
  const float* bn_cls_g = (const float*)d_in[11];
  const float* bn_cls_b = (const float*)d_in[12];
  const float* bn_cls_m = (const float*)d_in[13];
  const float* bn_cls_v = (const float*)d_in[14];
  const float* bn_box_g = (const float*)d_in[15];
  const float* bn_box_b = (const float*)d_in[16];
  const float* bn_box_m = (const float*)d_in[17];
  const float* bn_box_v = (const float*)d_in[18];
  const float* score_dw = (const float*)d_in[19];
  const float* score_pw = (const float*)d_in[20];
  const float* score_b = (const float*)d_in[21];
  const float* pred_dw = (const float*)d_in[22];
  const float* pred_pw = (const float*)d_in[23];
  const float* pred_b = (const float*)d_in[24];

  float* ws = (float*)d_ws;
  float* out = (float*)d_out;
  float* buf0 = ws;
  float* buf1 = ws + 2 * S;
  float* dv = buf1;                 // dv[subnet][c][pixel], exactly 2*S floats
  float* wcT = out;                 // 24576 floats; overwritten by head_gemm later
  float* wT = ws;                   // score weights [64][896] (buf0 reuse, post head_dw)
  float* wpT = ws + CH * WSTR_S;    // pred weights [64][64]

  dim3 blk(256);
  prep_stage_kernel<<<dim3(96), blk, 0, stream>>>(cls_pw, box_pw, wcT);
  stage_kernel<<<dim3(2 * TPS), blk, 0, stream>>>(
      p3, p4, p5, p6, p7, nullptr, buf0, cls_dw, box_dw, wcT, cls_pwb, box_pwb,
      bn_cls_g, bn_cls_b, bn_cls_m, bn_cls_v,
      bn_box_g, bn_box_b, bn_box_m, bn_box_v, 0);
  stage_kernel<<<dim3(2 * TPS), blk, 0, stream>>>(
      p3, p4, p5, p6, p7, buf0, buf1, cls_dw, box_dw, wcT, cls_pwb, box_pwb,
      bn_cls_g, bn_cls_b, bn_cls_m, bn_cls_v,
      bn_box_g, bn_box_b, bn_box_m, bn_box_v, 1);
  stage_kernel<<<dim3(2 * TPS), blk, 0, stream>>>(
      p3, p4, p5, p6, p7, buf1, buf0, cls_dw, box_dw, wcT, cls_pwb, box_pwb,
      bn_cls_g, bn_cls_b, bn_cls_m, bn_cls_v,
      bn_box_g, bn_box_b, bn_box_m, bn_box_v, 2);
  head_dw_kernel<<<dim3(2 * TPS), blk, 0, stream>>>(buf0, dv, score_dw, pred_dw);
  prep_head_kernel<<<dim3(240), blk, 0, stream>>>(score_pw, pred_pw, wT, wpT);
  head_gemm_kernel<<<dim3(GEMM_BLOCKS), blk, 0, stream>>>(
      dv, wT, wpT, score_b, pred_b, out);
}